// Round 4
// baseline (58.925 us; speedup 1.0000x reference)
//
#include <hip/hip_runtime.h>
#include <hip/hip_bf16.h>

// Bundle-adjustment residual.
// Strategy: kernel is gather-address-throughput-bound, so repack the gather
// tables into aligned float4 form in d_ws:
//   pose4[2*p+0] = (tx, ty, tz, qw)   (quat pre-normalized)
//   pose4[2*p+1] = (qx, qy, qz, 0)
//   patch4[q]    = (px, py, elev, 0)
// Main kernel: 3 aligned dwordx4 gathers per obs (was 10 scalar gathers).
// Streaming I/O uses clang ext_vector types + non-temporal hints so the
// 4.1 MB tables stay L2-resident.

#define NPOSES   4096
#define NPATCHES 262144

typedef float fvec4 __attribute__((ext_vector_type(4)));
typedef int   ivec4 __attribute__((ext_vector_type(4)));

__global__ __launch_bounds__(256) void pack_poses_kernel(
    const float* __restrict__ poses, fvec4* __restrict__ pose4, int n)
{
    int i = blockIdx.x * blockDim.x + threadIdx.x;
    if (i >= n) return;
    const float* p = poses + (size_t)i * 7;
    float tx = p[0], ty = p[1], tz = p[2];
    float qx = p[3], qy = p[4], qz = p[5], qw = p[6];
    float inv = rsqrtf(qx*qx + qy*qy + qz*qz + qw*qw);
    pose4[2*i + 0] = (fvec4){tx, ty, tz, qw * inv};
    pose4[2*i + 1] = (fvec4){qx * inv, qy * inv, qz * inv, 0.0f};
}

__global__ __launch_bounds__(256) void pack_patches_kernel(
    const float* __restrict__ patch_coords, const float* __restrict__ elev,
    fvec4* __restrict__ patch4, int n)
{
    int i = blockIdx.x * blockDim.x + threadIdx.x;
    if (i >= n) return;
    float2 pc = *reinterpret_cast<const float2*>(patch_coords + (size_t)i * 2);
    patch4[i] = (fvec4){pc.x, pc.y, elev[i], 0.0f};
}

__global__ __launch_bounds__(256) void ba_main_kernel(
    const fvec4* __restrict__ pose4,   // [2*NPOSES]
    const fvec4* __restrict__ patch4,  // [NPATCHES]
    const int*   __restrict__ poses_idx,
    const int*   __restrict__ patch_idx,
    const float* __restrict__ target,  // [NOBS,3]
    const float* __restrict__ weights, // [NOBS,1]
    float*       __restrict__ out,     // [NOBS,3]
    int n4)                            // NOBS/4
{
    int i4 = blockIdx.x * blockDim.x + threadIdx.x;
    if (i4 >= n4) return;

    // Streaming loads (non-temporal: don't evict gather tables from L2).
    ivec4 pidx = __builtin_nontemporal_load(reinterpret_cast<const ivec4*>(poses_idx) + i4);
    ivec4 qidx = __builtin_nontemporal_load(reinterpret_cast<const ivec4*>(patch_idx) + i4);
    fvec4 w4   = __builtin_nontemporal_load(reinterpret_cast<const fvec4*>(weights) + i4);
    const fvec4* tg4 = reinterpret_cast<const fvec4*>(target) + (size_t)i4 * 3;
    fvec4 t0 = __builtin_nontemporal_load(tg4 + 0);
    fvec4 t1 = __builtin_nontemporal_load(tg4 + 1);
    fvec4 t2 = __builtin_nontemporal_load(tg4 + 2);

    int   pi[4] = {pidx.x, pidx.y, pidx.z, pidx.w};
    int   qi[4] = {qidx.x, qidx.y, qidx.z, qidx.w};
    float ww[4] = {w4.x, w4.y, w4.z, w4.w};
    float tg[12] = {t0.x, t0.y, t0.z, t0.w,
                    t1.x, t1.y, t1.z, t1.w,
                    t2.x, t2.y, t2.z, t2.w};

    float res[12];

#pragma unroll
    for (int k = 0; k < 4; ++k) {
        // 3 aligned 16B gathers.
        fvec4 pa = pose4[2*pi[k] + 0];   // tx,ty,tz,qw (normalized)
        fvec4 pb = pose4[2*pi[k] + 1];   // qx,qy,qz,0
        fvec4 pp = patch4[qi[k]];        // px,py,pz,0

        float qx = pb.x, qy = pb.y, qz = pb.z, qw = pa.w;
        float px = pp.x, py = pp.y, pz = pp.z;

        // uv = cross(qv, pts)
        float ux = qy*pz - qz*py;
        float uy = qz*px - qx*pz;
        float uz = qx*py - qy*px;
        // cross(qv, uv)
        float cx = qy*uz - qz*uy;
        float cy = qz*ux - qx*uz;
        float cz = qx*uy - qy*ux;
        // rotated = pts + 2*(qw*uv + cross(qv,uv)) + t
        float rx = px + 2.0f*(qw*ux + cx) + pa.x;
        float ry = py + 2.0f*(qw*uy + cy) + pa.y;
        float rz = pz + 2.0f*(qw*uz + cz) + pa.z;

        // cart2polar (matches reference: r = sqrt(rho^2 + z^2))
        float rho = sqrtf(rx*rx + ry*ry);
        float r   = sqrtf(rho*rho + rz*rz);
        float az  = atan2f(ry, rx);
        float el  = atan2f(rz, rho);

        res[k*3 + 0] = (r  - tg[k*3 + 0]) * ww[k];
        res[k*3 + 1] = (az - tg[k*3 + 1]) * ww[k];
        res[k*3 + 2] = (el - tg[k*3 + 2]) * ww[k];
    }

    fvec4* o = reinterpret_cast<fvec4*>(out) + (size_t)i4 * 3;
    __builtin_nontemporal_store((fvec4){res[0], res[1], res[2],  res[3]},  o + 0);
    __builtin_nontemporal_store((fvec4){res[4], res[5], res[6],  res[7]},  o + 1);
    __builtin_nontemporal_store((fvec4){res[8], res[9], res[10], res[11]}, o + 2);
}

// Fallback (ws too small): direct kernel.
__global__ __launch_bounds__(256) void ba_fallback_kernel(
    const float* __restrict__ poses, const float* __restrict__ patch_coords,
    const float* __restrict__ elev, const int* __restrict__ poses_idx,
    const int* __restrict__ patch_idx, const float* __restrict__ target,
    const float* __restrict__ weights, float* __restrict__ out, int n)
{
    int i = blockIdx.x * blockDim.x + threadIdx.x;
    if (i >= n) return;
    int pi = poses_idx[i];
    int qi = patch_idx[i];
    const float* p = poses + (size_t)pi * 7;
    float tx = p[0], ty = p[1], tz = p[2];
    float qx = p[3], qy = p[4], qz = p[5], qw = p[6];
    float inv = rsqrtf(qx*qx + qy*qy + qz*qz + qw*qw);
    qx *= inv; qy *= inv; qz *= inv; qw *= inv;
    float2 pc = *reinterpret_cast<const float2*>(patch_coords + (size_t)qi * 2);
    float px = pc.x, py = pc.y, pz = elev[qi];
    float ux = qy*pz - qz*py, uy = qz*px - qx*pz, uz = qx*py - qy*px;
    float cx = qy*uz - qz*uy, cy = qz*ux - qx*uz, cz = qx*uy - qy*ux;
    float rx = px + 2.0f*(qw*ux + cx) + tx;
    float ry = py + 2.0f*(qw*uy + cy) + ty;
    float rz = pz + 2.0f*(qw*uz + cz) + tz;
    float rho = sqrtf(rx*rx + ry*ry);
    float r   = sqrtf(rho*rho + rz*rz);
    float az  = atan2f(ry, rx);
    float el  = atan2f(rz, rho);
    float w = weights[i];
    out[(size_t)i*3+0] = (r  - target[(size_t)i*3+0]) * w;
    out[(size_t)i*3+1] = (az - target[(size_t)i*3+1]) * w;
    out[(size_t)i*3+2] = (el - target[(size_t)i*3+2]) * w;
}

extern "C" void kernel_launch(void* const* d_in, const int* in_sizes, int n_in,
                              void* d_out, int out_size, void* d_ws, size_t ws_size,
                              hipStream_t stream) {
    const float* poses        = (const float*)d_in[0];
    const float* patch_coords = (const float*)d_in[1];
    const float* elev         = (const float*)d_in[2];
    const int*   poses_idx    = (const int*)d_in[3];
    const int*   patch_idx    = (const int*)d_in[4];
    const float* target       = (const float*)d_in[5];
    const float* weights      = (const float*)d_in[6];
    float*       out          = (float*)d_out;

    int n = in_sizes[3];  // NUM_OBS

    size_t patch_bytes = (size_t)NPATCHES * 16;        // 4 MiB
    size_t pose_bytes  = (size_t)NPOSES * 32;          // 128 KiB
    if (ws_size >= patch_bytes + pose_bytes) {
        fvec4* patch4 = (fvec4*)d_ws;
        fvec4* pose4  = (fvec4*)((char*)d_ws + patch_bytes);

        pack_poses_kernel<<<(NPOSES + 255) / 256, 256, 0, stream>>>(poses, pose4, NPOSES);
        pack_patches_kernel<<<(NPATCHES + 255) / 256, 256, 0, stream>>>(
            patch_coords, elev, patch4, NPATCHES);

        int n4 = n / 4;
        ba_main_kernel<<<(n4 + 255) / 256, 256, 0, stream>>>(
            pose4, patch4, poses_idx, patch_idx, target, weights, out, n4);
    } else {
        ba_fallback_kernel<<<(n + 255) / 256, 256, 0, stream>>>(
            poses, patch_coords, elev, poses_idx, patch_idx, target, weights, out, n);
    }
}

// Round 5
// 45.521 us; speedup vs baseline: 1.2945x; 1.2945x over previous
//
#include <hip/hip_runtime.h>
#include <hip/hip_bf16.h>

// Bundle-adjustment residual.
// R4 strategy: the kernel is gather-line-traffic-bound (each random 16B
// gather pulls a 128B line L2->L1; pose gathers are 2/3 of gather instrs).
// Fix: stage ALL poses (normalized) in 144KB dynamic LDS per 1024-thread
// block, stride 9 dwords (coprime with 32 banks -> random-row reads spread
// across banks). Patch stays a packed float4 table in d_ws (L2-resident).
// Global divergent gathers drop from 3 to 1 per observation.

#define NPOSES      4096
#define NPATCHES    262144
#define POSE_STRIDE 9   // dwords per pose in LDS (7 used + 2 pad)

typedef float fvec4 __attribute__((ext_vector_type(4)));
typedef int   ivec4 __attribute__((ext_vector_type(4)));

__global__ __launch_bounds__(256) void pack_patches_kernel(
    const float* __restrict__ patch_coords, const float* __restrict__ elev,
    fvec4* __restrict__ patch4, int n)
{
    int i = blockIdx.x * blockDim.x + threadIdx.x;
    if (i >= n) return;
    float2 pc = *reinterpret_cast<const float2*>(patch_coords + (size_t)i * 2);
    patch4[i] = (fvec4){pc.x, pc.y, elev[i], 0.0f};
}

__global__ __launch_bounds__(256) void pack_poses_kernel(
    const float* __restrict__ poses, fvec4* __restrict__ pose4, int n)
{
    int i = blockIdx.x * blockDim.x + threadIdx.x;
    if (i >= n) return;
    const float* p = poses + (size_t)i * 7;
    float tx = p[0], ty = p[1], tz = p[2];
    float qx = p[3], qy = p[4], qz = p[5], qw = p[6];
    float inv = rsqrtf(qx*qx + qy*qy + qz*qz + qw*qw);
    pose4[2*i + 0] = (fvec4){tx, ty, tz, qw * inv};
    pose4[2*i + 1] = (fvec4){qx * inv, qy * inv, qz * inv, 0.0f};
}

// Main kernel: poses in dynamic LDS, 4 obs per thread, 1024 threads/block.
__global__ __launch_bounds__(1024) void ba_lds_kernel(
    const float* __restrict__ poses,    // [4096,7] raw
    const fvec4* __restrict__ patch4,   // [NPATCHES] packed
    const int*   __restrict__ poses_idx,
    const int*   __restrict__ patch_idx,
    const float* __restrict__ target,   // [NOBS,3]
    const float* __restrict__ weights,  // [NOBS,1]
    float*       __restrict__ out,      // [NOBS,3]
    int n4)                             // NOBS/4
{
    extern __shared__ float lds[];      // NPOSES * POSE_STRIDE floats = 144KB
    int tid = threadIdx.x;

    // Stage + normalize 4 poses per thread (1024 threads * 4 = 4096).
#pragma unroll
    for (int j = 0; j < 4; ++j) {
        int p = tid * 4 + j;
        const float* src = poses + (size_t)p * 7;
        float tx = src[0], ty = src[1], tz = src[2];
        float qx = src[3], qy = src[4], qz = src[5], qw = src[6];
        float inv = rsqrtf(qx*qx + qy*qy + qz*qz + qw*qw);
        float* dst = lds + p * POSE_STRIDE;
        dst[0] = tx;      dst[1] = ty;      dst[2] = tz;
        dst[3] = qx*inv;  dst[4] = qy*inv;  dst[5] = qz*inv;  dst[6] = qw*inv;
    }
    __syncthreads();

    int i4 = blockIdx.x * blockDim.x + tid;
    if (i4 >= n4) return;

    // Streaming loads (non-temporal: keep patch table resident in L2).
    ivec4 pidx = __builtin_nontemporal_load(reinterpret_cast<const ivec4*>(poses_idx) + i4);
    ivec4 qidx = __builtin_nontemporal_load(reinterpret_cast<const ivec4*>(patch_idx) + i4);
    fvec4 w4   = __builtin_nontemporal_load(reinterpret_cast<const fvec4*>(weights) + i4);
    const fvec4* tg4 = reinterpret_cast<const fvec4*>(target) + (size_t)i4 * 3;
    fvec4 t0 = __builtin_nontemporal_load(tg4 + 0);
    fvec4 t1 = __builtin_nontemporal_load(tg4 + 1);
    fvec4 t2 = __builtin_nontemporal_load(tg4 + 2);

    int   pi[4] = {pidx.x, pidx.y, pidx.z, pidx.w};
    int   qi[4] = {qidx.x, qidx.y, qidx.z, qidx.w};
    float ww[4] = {w4.x, w4.y, w4.z, w4.w};
    float tg[12] = {t0.x, t0.y, t0.z, t0.w,
                    t1.x, t1.y, t1.z, t1.w,
                    t2.x, t2.y, t2.z, t2.w};

    float res[12];

#pragma unroll
    for (int k = 0; k < 4; ++k) {
        // Pose from LDS (7 dwords, stride-9 rows -> banks spread).
        const float* pl = lds + pi[k] * POSE_STRIDE;
        float tx = pl[0], ty = pl[1], tz = pl[2];
        float qx = pl[3], qy = pl[4], qz = pl[5], qw = pl[6];

        // Patch gather: the single global divergent load (16B, L2-resident).
        fvec4 pp = patch4[qi[k]];
        float px = pp.x, py = pp.y, pz = pp.z;

        // uv = cross(qv, pts)
        float ux = qy*pz - qz*py;
        float uy = qz*px - qx*pz;
        float uz = qx*py - qy*px;
        // cross(qv, uv)
        float cx = qy*uz - qz*uy;
        float cy = qz*ux - qx*uz;
        float cz = qx*uy - qy*ux;
        // rotated = pts + 2*(qw*uv + cross(qv,uv)) + t
        float rx = px + 2.0f*(qw*ux + cx) + tx;
        float ry = py + 2.0f*(qw*uy + cy) + ty;
        float rz = pz + 2.0f*(qw*uz + cz) + tz;

        // cart2polar (matches reference: r = sqrt(rho^2 + z^2))
        float rho = sqrtf(rx*rx + ry*ry);
        float r   = sqrtf(rho*rho + rz*rz);
        float az  = atan2f(ry, rx);
        float el  = atan2f(rz, rho);

        res[k*3 + 0] = (r  - tg[k*3 + 0]) * ww[k];
        res[k*3 + 1] = (az - tg[k*3 + 1]) * ww[k];
        res[k*3 + 2] = (el - tg[k*3 + 2]) * ww[k];
    }

    fvec4* o = reinterpret_cast<fvec4*>(out) + (size_t)i4 * 3;
    __builtin_nontemporal_store((fvec4){res[0], res[1], res[2],  res[3]},  o + 0);
    __builtin_nontemporal_store((fvec4){res[4], res[5], res[6],  res[7]},  o + 1);
    __builtin_nontemporal_store((fvec4){res[8], res[9], res[10], res[11]}, o + 2);
}

// Fallback path (R3 kernel): all-global float4 gathers.
__global__ __launch_bounds__(256) void ba_main_kernel(
    const fvec4* __restrict__ pose4, const fvec4* __restrict__ patch4,
    const int* __restrict__ poses_idx, const int* __restrict__ patch_idx,
    const float* __restrict__ target, const float* __restrict__ weights,
    float* __restrict__ out, int n4)
{
    int i4 = blockIdx.x * blockDim.x + threadIdx.x;
    if (i4 >= n4) return;
    ivec4 pidx = __builtin_nontemporal_load(reinterpret_cast<const ivec4*>(poses_idx) + i4);
    ivec4 qidx = __builtin_nontemporal_load(reinterpret_cast<const ivec4*>(patch_idx) + i4);
    fvec4 w4   = __builtin_nontemporal_load(reinterpret_cast<const fvec4*>(weights) + i4);
    const fvec4* tg4 = reinterpret_cast<const fvec4*>(target) + (size_t)i4 * 3;
    fvec4 t0 = __builtin_nontemporal_load(tg4 + 0);
    fvec4 t1 = __builtin_nontemporal_load(tg4 + 1);
    fvec4 t2 = __builtin_nontemporal_load(tg4 + 2);
    int   pi[4] = {pidx.x, pidx.y, pidx.z, pidx.w};
    int   qi[4] = {qidx.x, qidx.y, qidx.z, qidx.w};
    float ww[4] = {w4.x, w4.y, w4.z, w4.w};
    float tg[12] = {t0.x, t0.y, t0.z, t0.w, t1.x, t1.y, t1.z, t1.w,
                    t2.x, t2.y, t2.z, t2.w};
    float res[12];
#pragma unroll
    for (int k = 0; k < 4; ++k) {
        fvec4 pa = pose4[2*pi[k] + 0];
        fvec4 pb = pose4[2*pi[k] + 1];
        fvec4 pp = patch4[qi[k]];
        float qx = pb.x, qy = pb.y, qz = pb.z, qw = pa.w;
        float px = pp.x, py = pp.y, pz = pp.z;
        float ux = qy*pz - qz*py, uy = qz*px - qx*pz, uz = qx*py - qy*px;
        float cx = qy*uz - qz*uy, cy = qz*ux - qx*uz, cz = qx*uy - qy*ux;
        float rx = px + 2.0f*(qw*ux + cx) + pa.x;
        float ry = py + 2.0f*(qw*uy + cy) + pa.y;
        float rz = pz + 2.0f*(qw*uz + cz) + pa.z;
        float rho = sqrtf(rx*rx + ry*ry);
        float r   = sqrtf(rho*rho + rz*rz);
        float az  = atan2f(ry, rx);
        float el  = atan2f(rz, rho);
        res[k*3+0] = (r  - tg[k*3+0]) * ww[k];
        res[k*3+1] = (az - tg[k*3+1]) * ww[k];
        res[k*3+2] = (el - tg[k*3+2]) * ww[k];
    }
    fvec4* o = reinterpret_cast<fvec4*>(out) + (size_t)i4 * 3;
    __builtin_nontemporal_store((fvec4){res[0], res[1], res[2],  res[3]},  o + 0);
    __builtin_nontemporal_store((fvec4){res[4], res[5], res[6],  res[7]},  o + 1);
    __builtin_nontemporal_store((fvec4){res[8], res[9], res[10], res[11]}, o + 2);
}

extern "C" void kernel_launch(void* const* d_in, const int* in_sizes, int n_in,
                              void* d_out, int out_size, void* d_ws, size_t ws_size,
                              hipStream_t stream) {
    const float* poses        = (const float*)d_in[0];
    const float* patch_coords = (const float*)d_in[1];
    const float* elev         = (const float*)d_in[2];
    const int*   poses_idx    = (const int*)d_in[3];
    const int*   patch_idx    = (const int*)d_in[4];
    const float* target       = (const float*)d_in[5];
    const float* weights      = (const float*)d_in[6];
    float*       out          = (float*)d_out;

    int n  = in_sizes[3];  // NUM_OBS
    int n4 = n / 4;

    size_t patch_bytes = (size_t)NPATCHES * 16;  // 4 MiB
    size_t pose_bytes  = (size_t)NPOSES * 32;    // 128 KiB
    size_t lds_bytes   = (size_t)NPOSES * POSE_STRIDE * 4;  // 147456 B

    fvec4* patch4 = (fvec4*)d_ws;
    fvec4* pose4  = (fvec4*)((char*)d_ws + patch_bytes);

    pack_patches_kernel<<<(NPATCHES + 255) / 256, 256, 0, stream>>>(
        patch_coords, elev, patch4, NPATCHES);

    // Opt in to >64KB dynamic LDS (idempotent; not a stream op).
    hipError_t attr_err = hipFuncSetAttribute(
        reinterpret_cast<const void*>(ba_lds_kernel),
        hipFuncAttributeMaxDynamicSharedMemorySize, (int)lds_bytes);

    if (attr_err == hipSuccess && ws_size >= patch_bytes) {
        int block = 1024;
        int grid  = (n4 + block - 1) / block;  // 512
        ba_lds_kernel<<<grid, block, lds_bytes, stream>>>(
            poses, patch4, poses_idx, patch_idx, target, weights, out, n4);
    } else {
        pack_poses_kernel<<<(NPOSES + 255) / 256, 256, 0, stream>>>(poses, pose4, NPOSES);
        ba_main_kernel<<<(n4 + 255) / 256, 256, 0, stream>>>(
            pose4, patch4, poses_idx, patch_idx, target, weights, out, n4);
    }
}